// Round 2
// baseline (3264.640 us; speedup 1.0000x reference)
//
#include <hip/hip_runtime.h>
#include <cmath>

typedef _Float16 half_t;
typedef __attribute__((ext_vector_type(8))) _Float16 half8;
typedef __attribute__((ext_vector_type(2))) _Float16 half2v;
typedef __attribute__((ext_vector_type(4))) float f32x4;

#define T_TOK   9216
#define DIN     1024
#define DMOD    2048
#define HDIM    8192
#define NEXP    4
#define CAPN    3456          // int(1.5 * 9216 / 4)
#define GAP_TAU 5e-5          // top-2 gap below which we recompute logits in fp64

__device__ inline float geluf(float x) {
    return 0.5f * x * (1.0f + erff(x * 0.70710678118654752440f));
}
__device__ inline double gelud(double x) {
    return 0.5 * x * (1.0 + erf(x * 0.70710678118654752440));
}
__device__ inline double waveRedD(double v) {
#pragma unroll
    for (int off = 32; off; off >>= 1) v += __shfl_down(v, off);
    return v;
}

// ---------------------------------------------------------------- K1: LayerNorm (fp64 reductions)
__global__ __launch_bounds__(256) void k1_ln(const float* __restrict__ x,
                                             const float* __restrict__ g,
                                             const float* __restrict__ b,
                                             float* __restrict__ xn) {
    const int row = blockIdx.x;
    const int tid = threadIdx.x;
    const int c = tid * 4;
    const float4 v = *(const float4*)&x[(size_t)row * DIN + c];
    __shared__ double sw[8];
    __shared__ double bc[2];
    const int lane = tid & 63, wv = tid >> 6;

    double s = (double)v.x + (double)v.y + (double)v.z + (double)v.w;
    s = waveRedD(s);
    if (lane == 0) sw[wv] = s;
    __syncthreads();
    if (tid == 0) bc[0] = (sw[0] + sw[1] + sw[2] + sw[3]) * (1.0 / 1024.0);
    __syncthreads();
    const double mu = bc[0];
    const double d0 = (double)v.x - mu, d1 = (double)v.y - mu;
    const double d2 = (double)v.z - mu, d3 = (double)v.w - mu;
    double s2 = d0 * d0 + d1 * d1 + d2 * d2 + d3 * d3;
    s2 = waveRedD(s2);
    if (lane == 0) sw[4 + wv] = s2;
    __syncthreads();
    if (tid == 0) bc[1] = 1.0 / sqrt((sw[4] + sw[5] + sw[6] + sw[7]) * (1.0 / 1024.0) + 1e-5);
    __syncthreads();
    const double rs = bc[1];
    const float4 gv = *(const float4*)&g[c];
    const float4 bv = *(const float4*)&b[c];
    float4 o;
    o.x = (float)(d0 * rs * (double)gv.x + (double)bv.x);
    o.y = (float)(d1 * rs * (double)gv.y + (double)bv.y);
    o.z = (float)(d2 * rs * (double)gv.z + (double)bv.z);
    o.w = (float)(d3 * rs * (double)gv.w + (double)bv.w);
    *(float4*)&xn[(size_t)row * DIN + c] = o;
}

// ---------------------------------------------------------------- K2: pre_linear fp32 GEMM + GELU
#define K2_BK 16
#define K2_AST 132
#define K2_BST 132
__global__ __launch_bounds__(256) void k2_pre(const float* __restrict__ xn,
                                              const float* __restrict__ W,
                                              const float* __restrict__ bias,
                                              float* __restrict__ t32,
                                              half_t* __restrict__ t16) {
    __shared__ float As[K2_BK * K2_AST];
    __shared__ float Bs[K2_BK * K2_BST];
    const int tid = threadIdx.x;
    const int m0 = blockIdx.y * 128;
    const int n0 = blockIdx.x * 128;
    const int ar = tid >> 1;            // A stage row 0..127
    const int ak = (tid & 1) * 8;       // A stage k offset
    const int bk = tid >> 4;            // B stage k row 0..15
    const int bn = (tid & 15) * 4;      // B stage n offset 0..60
    const int rm = (tid >> 4) * 4;      // compute rows base
    const int rn = (tid & 15) * 4;      // compute cols base

    float acc[8][8];
#pragma unroll
    for (int i = 0; i < 8; ++i)
#pragma unroll
        for (int j = 0; j < 8; ++j) acc[i][j] = 0.0f;

    for (int k0 = 0; k0 < DIN; k0 += K2_BK) {
        const float4 a0 = *(const float4*)&xn[(size_t)(m0 + ar) * DIN + k0 + ak];
        const float4 a1 = *(const float4*)&xn[(size_t)(m0 + ar) * DIN + k0 + ak + 4];
        const float* wp = &W[(size_t)(k0 + bk) * DMOD + n0 + bn];
        const float4 b0 = *(const float4*)wp;
        const float4 b1v = *(const float4*)(wp + 64);
        __syncthreads();
        As[(ak + 0) * K2_AST + ar] = a0.x;
        As[(ak + 1) * K2_AST + ar] = a0.y;
        As[(ak + 2) * K2_AST + ar] = a0.z;
        As[(ak + 3) * K2_AST + ar] = a0.w;
        As[(ak + 4) * K2_AST + ar] = a1.x;
        As[(ak + 5) * K2_AST + ar] = a1.y;
        As[(ak + 6) * K2_AST + ar] = a1.z;
        As[(ak + 7) * K2_AST + ar] = a1.w;
        *(float4*)&Bs[bk * K2_BST + bn] = b0;
        *(float4*)&Bs[bk * K2_BST + bn + 64] = b1v;
        __syncthreads();
#pragma unroll
        for (int kk = 0; kk < K2_BK; ++kk) {
            const float4 av0 = *(const float4*)&As[kk * K2_AST + rm];
            const float4 av1 = *(const float4*)&As[kk * K2_AST + rm + 64];
            const float4 bv0 = *(const float4*)&Bs[kk * K2_BST + rn];
            const float4 bv1 = *(const float4*)&Bs[kk * K2_BST + rn + 64];
            const float a[8] = {av0.x, av0.y, av0.z, av0.w, av1.x, av1.y, av1.z, av1.w};
            const float bb[8] = {bv0.x, bv0.y, bv0.z, bv0.w, bv1.x, bv1.y, bv1.z, bv1.w};
#pragma unroll
            for (int i = 0; i < 8; ++i)
#pragma unroll
                for (int j = 0; j < 8; ++j) acc[i][j] += a[i] * bb[j];
        }
    }
#pragma unroll
    for (int i = 0; i < 8; ++i) {
        const int m = m0 + ((i < 4) ? (rm + i) : (64 + rm + i - 4));
#pragma unroll
        for (int j = 0; j < 8; ++j) {
            const int n = n0 + ((j < 4) ? (rn + j) : (64 + rn + j - 4));
            const float z = acc[i][j] + bias[n];
            const float t = geluf(z);
            t32[(size_t)m * DMOD + n] = t;
            t16[(size_t)m * DMOD + n] = (half_t)t;
        }
    }
}

// ---------------------------------------------------------------- K3: router logits (fp64 from fp32 t) + gap flags
__global__ __launch_bounds__(256) void k3_router(const float* __restrict__ t32,
                                                 const float* __restrict__ swW,
                                                 const float* __restrict__ swb,
                                                 double* __restrict__ logitsD,
                                                 int* __restrict__ flags) {
    const int tok = blockIdx.x * 4 + (threadIdx.x >> 6);
    const int lane = threadIdx.x & 63;
    const float* tr = t32 + (size_t)tok * DMOD;
    double a0 = 0, a1 = 0, a2 = 0, a3 = 0;
    for (int it = 0; it < 8; ++it) {
        const int k = it * 256 + lane * 4;
        const float4 tv = *(const float4*)&tr[k];
        const float tp[4] = {tv.x, tv.y, tv.z, tv.w};
#pragma unroll
        for (int j = 0; j < 4; ++j) {
            const float4 wv = *(const float4*)&swW[(size_t)(k + j) * 4];
            const double td = (double)tp[j];
            a0 += td * (double)wv.x;
            a1 += td * (double)wv.y;
            a2 += td * (double)wv.z;
            a3 += td * (double)wv.w;
        }
    }
    a0 = waveRedD(a0); a1 = waveRedD(a1); a2 = waveRedD(a2); a3 = waveRedD(a3);
    if (lane == 0) {
        a0 += (double)swb[0]; a1 += (double)swb[1]; a2 += (double)swb[2]; a3 += (double)swb[3];
        double* Lp = logitsD + (size_t)tok * 4;
        Lp[0] = a0; Lp[1] = a1; Lp[2] = a2; Lp[3] = a3;
        double m1 = a0, m2 = -1e300;
        if (a1 > m1) { m2 = m1; m1 = a1; } else if (a1 > m2) m2 = a1;
        if (a2 > m1) { m2 = m1; m1 = a2; } else if (a2 > m2) m2 = a2;
        if (a3 > m1) { m2 = m1; m1 = a3; } else if (a3 > m2) m2 = a3;
        flags[tok] = (m1 - m2 < GAP_TAU) ? 1 : 0;
    }
}

// ---------------------------------------------------------------- K4: full fp64 recompute (from raw x) of flagged tokens' logits
__global__ __launch_bounds__(256) void k4_recompute(const float* __restrict__ x,
                                                    const float* __restrict__ g,
                                                    const float* __restrict__ bvec,
                                                    const float* __restrict__ preW,
                                                    const float* __restrict__ preb,
                                                    const float* __restrict__ swW,
                                                    const float* __restrict__ swb,
                                                    const int* __restrict__ flags,
                                                    double* __restrict__ logitsD) {
    const int tok = blockIdx.x;
    if (!flags[tok]) return;
    __shared__ double xr[DIN];
    __shared__ double sw8[8];
    __shared__ double bcv[2];
    __shared__ double r4[4][4];
    const int tid = threadIdx.x, lane = tid & 63, wv = tid >> 6;

    double s = 0;
    for (int i = tid; i < DIN; i += 256) {
        const double v = (double)x[(size_t)tok * DIN + i];
        xr[i] = v;
        s += v;
    }
    s = waveRedD(s);
    if (lane == 0) sw8[wv] = s;
    __syncthreads();
    if (tid == 0) bcv[0] = (sw8[0] + sw8[1] + sw8[2] + sw8[3]) * (1.0 / 1024.0);
    __syncthreads();
    const double mu = bcv[0];
    double s2 = 0;
    for (int i = tid; i < DIN; i += 256) {
        const double d = xr[i] - mu;
        s2 += d * d;
    }
    s2 = waveRedD(s2);
    if (lane == 0) sw8[4 + wv] = s2;
    __syncthreads();
    if (tid == 0) bcv[1] = 1.0 / sqrt((sw8[4] + sw8[5] + sw8[6] + sw8[7]) * (1.0 / 1024.0) + 1e-5);
    __syncthreads();
    const double rs = bcv[1];
    for (int i = tid; i < DIN; i += 256)  // each i touched by exactly one thread: no race
        xr[i] = (xr[i] - mu) * rs * (double)g[i] + (double)bvec[i];
    __syncthreads();

    double l0 = 0, l1 = 0, l2 = 0, l3 = 0;
    for (int p = 0; p < 8; ++p) {
        const int c = p * 256 + tid;
        double z = (double)preb[c];
#pragma unroll 8
        for (int k = 0; k < DIN; ++k)
            z += xr[k] * (double)preW[(size_t)k * DMOD + c];
        const double t = gelud(z);
        const float4 wv4 = *(const float4*)&swW[(size_t)c * 4];
        l0 += t * (double)wv4.x; l1 += t * (double)wv4.y;
        l2 += t * (double)wv4.z; l3 += t * (double)wv4.w;
    }
    l0 = waveRedD(l0); l1 = waveRedD(l1); l2 = waveRedD(l2); l3 = waveRedD(l3);
    if (lane == 0) { r4[wv][0] = l0; r4[wv][1] = l1; r4[wv][2] = l2; r4[wv][3] = l3; }
    __syncthreads();
    if (tid == 0) {
#pragma unroll
        for (int e = 0; e < 4; ++e)
            logitsD[(size_t)tok * 4 + e] =
                r4[0][e] + r4[1][e] + r4[2][e] + r4[3][e] + (double)swb[e];
    }
}

// ---------------------------------------------------------------- K5: softmax + argmax + capacity scan (single block)
__global__ __launch_bounds__(1024) void k5_scan(const double* __restrict__ logitsD,
                                                int* __restrict__ slot2tok,
                                                int* __restrict__ keepArr,
                                                int* __restrict__ keptcnt,
                                                float* __restrict__ outCounts,
                                                float* __restrict__ outPsum,
                                                float* __restrict__ outNdrop,
                                                float* __restrict__ outPmax) {
    __shared__ unsigned long long sc[1024];
    __shared__ double red[1024];
    __shared__ unsigned int baseSh[4];
    const int tid = threadIdx.x;
    for (int i = tid; i < NEXP * CAPN; i += 1024) slot2tok[i] = 0;
    if (tid < 4) baseSh[tid] = 0;
    double p0 = 0, p1 = 0, p2 = 0, p3 = 0;
    __syncthreads();
    for (int c = 0; c < 9; ++c) {
        const int tok = c * 1024 + tid;
        const double* L = logitsD + (size_t)tok * 4;
        const double l0 = L[0], l1 = L[1], l2 = L[2], l3 = L[3];
        int r = 0;
        double m = l0;
        if (l1 > m) { m = l1; r = 1; }
        if (l2 > m) { m = l2; r = 2; }
        if (l3 > m) { m = l3; r = 3; }
        const double e0 = exp(l0 - m), e1 = exp(l1 - m), e2 = exp(l2 - m), e3 = exp(l3 - m);
        const double inv = 1.0 / (e0 + e1 + e2 + e3);
        p0 += e0 * inv; p1 += e1 * inv; p2 += e2 * inv; p3 += e3 * inv;
        outPmax[tok] = (float)inv;  // prob of argmax = exp(0)*inv
        const unsigned long long oh = 1ull << (r * 16);
        sc[tid] = oh;
        __syncthreads();
        for (int off = 1; off < 1024; off <<= 1) {
            const unsigned long long add = (tid >= off) ? sc[tid - off] : 0ull;
            __syncthreads();
            sc[tid] += add;
            __syncthreads();
        }
        const unsigned long long incl = sc[tid];
        const unsigned int pic = (unsigned int)((incl >> (r * 16)) & 0xFFFFull) - 1u;
        const unsigned int pos = baseSh[r] + pic;
        const int kp = (pos < (unsigned int)CAPN) ? 1 : 0;
        keepArr[tok] = kp;
        if (kp) slot2tok[r * CAPN + pos] = tok;
        __syncthreads();
        if (tid == 1023) {
            baseSh[0] += (unsigned int)(incl & 0xFFFFull);
            baseSh[1] += (unsigned int)((incl >> 16) & 0xFFFFull);
            baseSh[2] += (unsigned int)((incl >> 32) & 0xFFFFull);
            baseSh[3] += (unsigned int)((incl >> 48) & 0xFFFFull);
        }
        __syncthreads();
    }
    if (tid < 4) {
        const unsigned int cnt = baseSh[tid];
        outCounts[tid] = (float)cnt;
        keptcnt[tid] = (cnt < (unsigned int)CAPN) ? (int)cnt : CAPN;
    }
    if (tid == 0) {
        int nd = 0;
#pragma unroll
        for (int e = 0; e < 4; ++e)
            nd += (baseSh[e] > (unsigned int)CAPN) ? (int)(baseSh[e] - CAPN) : 0;
        outNdrop[0] = (float)nd;
    }
    const double ps[4] = {p0, p1, p2, p3};
    for (int e = 0; e < 4; ++e) {
        __syncthreads();
        red[tid] = ps[e];
        __syncthreads();
        for (int off = 512; off > 0; off >>= 1) {
            if (tid < off) red[tid] += red[tid + off];
            __syncthreads();
        }
        if (tid == 0) outPsum[e] = (float)red[0];
    }
}

// ---------------------------------------------------------------- K6: expert GEMM1 (fp16 MFMA): h = gelu(X @ W1 + b1)
#define G_ST 40  // LDS row stride in halves (80B: 16B-aligned b128 rows)
__global__ __launch_bounds__(256) void k6_ffn1(const half_t* __restrict__ t16,
                                               const float* __restrict__ W1e,
                                               const float* __restrict__ b1e,
                                               const int* __restrict__ s2t,
                                               const int* __restrict__ keptp,
                                               half_t* __restrict__ hbuf) {
    const int kept = keptp[0];
    const int m0 = blockIdx.y * 128;
    if (m0 >= kept) return;
    const int n0 = blockIdx.x * 128;
    __shared__ half_t As[128 * G_ST];
    __shared__ half_t Bs[128 * G_ST];
    const int tid = threadIdx.x;
    const int ar = tid >> 1;
    const int aseg = (tid & 1) * 16;       // halves [aseg, aseg+16) of the 32-half row
    const int tokA = s2t[m0 + ar];
    const size_t abase = (size_t)tokA * DMOD + aseg;
    const int bk2 = (tid >> 4) * 2;
    const int bn4 = (tid & 15) * 4;
    const int w = tid >> 6, lane = tid & 63;
    const int q = lane >> 4, mr = lane & 15;
    const int wm = (w & 1) * 64, wn = (w >> 1) * 64;

    f32x4 acc[4][4];
#pragma unroll
    for (int i = 0; i < 4; ++i)
#pragma unroll
        for (int j = 0; j < 4; ++j) acc[i][j] = (f32x4){0.f, 0.f, 0.f, 0.f};

    for (int k0 = 0; k0 < DMOD; k0 += 32) {
        const uint4 av0 = *(const uint4*)&t16[abase + k0];      // 8 halves
        const uint4 av1 = *(const uint4*)&t16[abase + k0 + 8];  // 8 halves
        const float* wp = &W1e[(size_t)(k0 + bk2) * HDIM + n0 + bn4];
        const float4 f0 = *(const float4*)wp;
        const float4 f1 = *(const float4*)(wp + 64);
        const float4 f2 = *(const float4*)(wp + HDIM);
        const float4 f3 = *(const float4*)(wp + HDIM + 64);
        __syncthreads();
        *(uint4*)&As[ar * G_ST + aseg] = av0;
        *(uint4*)&As[ar * G_ST + aseg + 8] = av1;
        const float fa0[4] = {f0.x, f0.y, f0.z, f0.w};
        const float fa1[4] = {f1.x, f1.y, f1.z, f1.w};
        const float fa2[4] = {f2.x, f2.y, f2.z, f2.w};
        const float fa3[4] = {f3.x, f3.y, f3.z, f3.w};
#pragma unroll
        for (int j = 0; j < 4; ++j) {
            half2v v;
            v.x = (_Float16)fa0[j]; v.y = (_Float16)fa2[j];
            *(half2v*)&Bs[(bn4 + j) * G_ST + bk2] = v;
            half2v u;
            u.x = (_Float16)fa1[j]; u.y = (_Float16)fa3[j];
            *(half2v*)&Bs[(bn4 + 64 + j) * G_ST + bk2] = u;
        }
        __syncthreads();
        half8 afr[4], bfr[4];
#pragma unroll
        for (int i = 0; i < 4; ++i)
            afr[i] = *(const half8*)&As[(wm + i * 16 + mr) * G_ST + q * 8];
#pragma unroll
        for (int j = 0; j < 4; ++j)
            bfr[j] = *(const half8*)&Bs[(wn + j * 16 + mr) * G_ST + q * 8];
#pragma unroll
        for (int i = 0; i < 4; ++i)
#pragma unroll
            for (int j = 0; j < 4; ++j)
                acc[i][j] = __builtin_amdgcn_mfma_f32_16x16x32_f16(afr[i], bfr[j], acc[i][j], 0, 0, 0);
    }
    float bb[4];
#pragma unroll
    for (int j = 0; j < 4; ++j) bb[j] = b1e[n0 + wn + j * 16 + mr];
#pragma unroll
    for (int i = 0; i < 4; ++i) {
#pragma unroll
        for (int p = 0; p < 4; ++p) {
            const int row = m0 + wm + i * 16 + q * 4 + p;
            half_t* hp = hbuf + (size_t)row * HDIM;
#pragma unroll
            for (int j = 0; j < 4; ++j) {
                const int col = n0 + wn + j * 16 + mr;
                const float z = acc[i][j][p] + bb[j];
                hp[col] = (half_t)geluf(z);
            }
        }
    }
}

// ---------------------------------------------------------------- K7: expert GEMM2 (fp16 MFMA): final[tok] = (h @ W2 + b2) * pmax
__global__ __launch_bounds__(256) void k7_ffn2(const half_t* __restrict__ hbuf,
                                               const float* __restrict__ W2e,
                                               const float* __restrict__ b2e,
                                               const int* __restrict__ s2t,
                                               const int* __restrict__ keptp,
                                               const float* __restrict__ pmax,
                                               float* __restrict__ outF) {
    const int kept = keptp[0];
    const int m0 = blockIdx.y * 128;
    if (m0 >= kept) return;
    const int n0 = blockIdx.x * 128;
    __shared__ half_t As[128 * G_ST];
    __shared__ half_t Bs[128 * G_ST];
    const int tid = threadIdx.x;
    const int ar = tid >> 1;
    const int aseg = (tid & 1) * 16;
    const size_t abase = (size_t)(m0 + ar) * HDIM + aseg;
    const int bk2 = (tid >> 4) * 2;
    const int bn4 = (tid & 15) * 4;
    const int w = tid >> 6, lane = tid & 63;
    const int q = lane >> 4, mr = lane & 15;
    const int wm = (w & 1) * 64, wn = (w >> 1) * 64;

    f32x4 acc[4][4];
#pragma unroll
    for (int i = 0; i < 4; ++i)
#pragma unroll
        for (int j = 0; j < 4; ++j) acc[i][j] = (f32x4){0.f, 0.f, 0.f, 0.f};

    for (int k0 = 0; k0 < HDIM; k0 += 32) {
        const uint4 av0 = *(const uint4*)&hbuf[abase + k0];
        const uint4 av1 = *(const uint4*)&hbuf[abase + k0 + 8];
        const float* wp = &W2e[(size_t)(k0 + bk2) * DMOD + n0 + bn4];
        const float4 f0 = *(const float4*)wp;
        const float4 f1 = *(const float4*)(wp + 64);
        const float4 f2 = *(const float4*)(wp + DMOD);
        const float4 f3 = *(const float4*)(wp + DMOD + 64);
        __syncthreads();
        *(uint4*)&As[ar * G_ST + aseg] = av0;
        *(uint4*)&As[ar * G_ST + aseg + 8] = av1;
        const float fa0[4] = {f0.x, f0.y, f0.z, f0.w};
        const float fa1[4] = {f1.x, f1.y, f1.z, f1.w};
        const float fa2[4] = {f2.x, f2.y, f2.z, f2.w};
        const float fa3[4] = {f3.x, f3.y, f3.z, f3.w};
#pragma unroll
        for (int j = 0; j < 4; ++j) {
            half2v v;
            v.x = (_Float16)fa0[j]; v.y = (_Float16)fa2[j];
            *(half2v*)&Bs[(bn4 + j) * G_ST + bk2] = v;
            half2v u;
            u.x = (_Float16)fa1[j]; u.y = (_Float16)fa3[j];
            *(half2v*)&Bs[(bn4 + 64 + j) * G_ST + bk2] = u;
        }
        __syncthreads();
        half8 afr[4], bfr[4];
#pragma unroll
        for (int i = 0; i < 4; ++i)
            afr[i] = *(const half8*)&As[(wm + i * 16 + mr) * G_ST + q * 8];
#pragma unroll
        for (int j = 0; j < 4; ++j)
            bfr[j] = *(const half8*)&Bs[(wn + j * 16 + mr) * G_ST + q * 8];
#pragma unroll
        for (int i = 0; i < 4; ++i)
#pragma unroll
            for (int j = 0; j < 4; ++j)
                acc[i][j] = __builtin_amdgcn_mfma_f32_16x16x32_f16(afr[i], bfr[j], acc[i][j], 0, 0, 0);
    }
    float bb[4];
#pragma unroll
    for (int j = 0; j < 4; ++j) bb[j] = b2e[n0 + wn + j * 16 + mr];
#pragma unroll
    for (int i = 0; i < 4; ++i) {
#pragma unroll
        for (int p = 0; p < 4; ++p) {
            const int gm = m0 + wm + i * 16 + q * 4 + p;
            if (gm < kept) {
                const int tok = s2t[gm];
                const float pm = pmax[tok];
                float* op = outF + (size_t)tok * DMOD;
#pragma unroll
                for (int j = 0; j < 4; ++j) {
                    const int col = n0 + wn + j * 16 + mr;
                    op[col] = (acc[i][j][p] + bb[j]) * pm;
                }
            }
        }
    }
}

// ---------------------------------------------------------------- K8: dropped-token passthrough
__global__ __launch_bounds__(256) void k8_pass(const int* __restrict__ keepArr,
                                               const float* __restrict__ t32,
                                               const float* __restrict__ pmax,
                                               float* __restrict__ outF) {
    const int tok = blockIdx.x;
    if (keepArr[tok]) return;
    const float pm = pmax[tok];
    const size_t base = (size_t)tok * DMOD;
    for (int c = threadIdx.x * 4; c < DMOD; c += 1024) {
        float4 v = *(const float4*)&t32[base + c];
        v.x *= pm; v.y *= pm; v.z *= pm; v.w *= pm;
        *(float4*)&outF[base + c] = v;
    }
}

// ---------------------------------------------------------------- launch
extern "C" void kernel_launch(void* const* d_in, const int* in_sizes, int n_in,
                              void* d_out, int out_size, void* d_ws, size_t ws_size,
                              hipStream_t stream) {
    const float* x     = (const float*)d_in[0];
    const float* ln_g  = (const float*)d_in[1];
    const float* ln_b  = (const float*)d_in[2];
    const float* pre_W = (const float*)d_in[3];
    const float* pre_b = (const float*)d_in[4];
    const float* sw_W  = (const float*)d_in[5];
    const float* sw_b  = (const float*)d_in[6];
    const float* W1    = (const float*)d_in[7];
    const float* b1    = (const float*)d_in[8];
    const float* W2    = (const float*)d_in[9];
    const float* b2    = (const float*)d_in[10];

    float* outF      = (float*)d_out;
    float* outCounts = outF + (size_t)T_TOK * DMOD;
    float* outPsum   = outCounts + 4;
    float* outNdrop  = outPsum + 4;
    float* outPmax   = outNdrop + 1;

    char* w = (char*)d_ws;
    const size_t OFF_XN  = 0;
    const size_t OFF_T32 = OFF_XN + (size_t)T_TOK * DIN * 4;
    const size_t OFF_T16 = OFF_T32 + (size_t)T_TOK * DMOD * 4;
    const size_t OFF_H   = OFF_T16 + (size_t)T_TOK * DMOD * 2;
    const size_t OFF_LG  = OFF_H + (size_t)CAPN * HDIM * 2;
    const size_t OFF_FL  = OFF_LG + (size_t)T_TOK * 4 * 8;
    const size_t OFF_KP  = OFF_FL + (size_t)T_TOK * 4;
    const size_t OFF_ST  = OFF_KP + (size_t)T_TOK * 4;
    const size_t OFF_KC  = OFF_ST + (size_t)NEXP * CAPN * 4;
    const size_t REQ     = OFF_KC + 256;
    if (ws_size < REQ) return;

    float*  xn      = (float*)(w + OFF_XN);
    float*  t32     = (float*)(w + OFF_T32);
    half_t* t16     = (half_t*)(w + OFF_T16);
    half_t* hbuf    = (half_t*)(w + OFF_H);
    double* logitsD = (double*)(w + OFF_LG);
    int*    flags   = (int*)(w + OFF_FL);
    int*    keepArr = (int*)(w + OFF_KP);
    int*    s2t     = (int*)(w + OFF_ST);
    int*    keptcnt = (int*)(w + OFF_KC);

    k1_ln<<<T_TOK, 256, 0, stream>>>(x, ln_g, ln_b, xn);
    k2_pre<<<dim3(DMOD / 128, T_TOK / 128), 256, 0, stream>>>(xn, pre_W, pre_b, t32, t16);
    k3_router<<<T_TOK / 4, 256, 0, stream>>>(t32, sw_W, sw_b, logitsD, flags);
    k4_recompute<<<T_TOK, 256, 0, stream>>>(x, ln_g, ln_b, pre_W, pre_b, sw_W, sw_b,
                                            flags, logitsD);
    k5_scan<<<1, 1024, 0, stream>>>(logitsD, s2t, keepArr, keptcnt,
                                    outCounts, outPsum, outNdrop, outPmax);
    for (int e = 0; e < NEXP; ++e) {
        k6_ffn1<<<dim3(HDIM / 128, CAPN / 128), 256, 0, stream>>>(
            t16, W1 + (size_t)e * DMOD * HDIM, b1 + (size_t)e * HDIM,
            s2t + (size_t)e * CAPN, keptcnt + e, hbuf);
        k7_ffn2<<<dim3(DMOD / 128, CAPN / 128), 256, 0, stream>>>(
            hbuf, W2 + (size_t)e * HDIM * DMOD, b2 + (size_t)e * DMOD,
            s2t + (size_t)e * CAPN, keptcnt + e, outPmax, outF);
    }
    k8_pass<<<T_TOK, 256, 0, stream>>>(keepArr, t32, outPmax, outF);
}